// Round 6
// baseline (111.324 us; speedup 1.0000x reference)
//
#include <hip/hip_runtime.h>
#include <hip/hip_bf16.h>
#include <float.h>

typedef float f32x4 __attribute__((ext_vector_type(4)));
typedef int i32x4 __attribute__((ext_vector_type(4)));

#define SCOPE_AGENT __HIP_MEMORY_SCOPE_AGENT

// ---------------- argmax helper ----------------
// Argmax of R consecutive rows (row = t*batch + b) by one 64-lane wave.
// Skips rows with t >= lengths[b] (never consumed downstream).
// If ATOMIC_ML, results are stored with agent-scope atomic stores (coherent
// across XCDs for the fused single-kernel path); else plain stores.
template <int R, bool ATOMIC_ML>
__device__ __forceinline__ void argmax_tasks(const float* __restrict__ x,
                                             int* __restrict__ ml,
                                             const int* __restrict__ lengths,
                                             int row0, int nrows,
                                             int seq_len, int batch, int vocab,
                                             int lane) {
    bool act[R];
    int tt[R], bb[R];
    bool any = false;
    int len_lane = 0;
    if (batch <= 64) len_lane = lengths[lane < batch ? lane : 0];
#pragma unroll
    for (int r = 0; r < R; ++r) {
        const int row = row0 + r;
        if (row < nrows) {
            const int t = row / batch;
            const int b = row - t * batch;
            tt[r] = t; bb[r] = b;
            const int len = (batch <= 64) ? __shfl(len_lane, b, 64) : lengths[b];
            act[r] = (t < len);
        } else {
            act[r] = false; tt[r] = 0; bb[r] = 0;
        }
        any |= act[r];
    }
    if (!any) return;

    float best[R];
    int bidx[R];
#pragma unroll
    for (int r = 0; r < R; ++r) { best[r] = -FLT_MAX; bidx[r] = vocab; }

    const int vocab4 = vocab & ~3;
    for (int base = lane * 4; base < vocab4; base += 256) {
#pragma unroll
        for (int r = 0; r < R; ++r) {
            if (!act[r]) continue;
            f32x4 v = *reinterpret_cast<const f32x4*>(
                x + (size_t)(row0 + r) * vocab + base);
#pragma unroll
            for (int j = 0; j < 4; ++j) {
                if (v[j] > best[r]) { best[r] = v[j]; bidx[r] = base + j; }
            }
        }
    }
    // Scalar tail (vocab % 4 != 0); tail indices exceed main-loop indices,
    // strict '>' keeps the earlier occurrence.
    for (int i = vocab4 + lane; i < vocab; i += 64) {
#pragma unroll
        for (int r = 0; r < R; ++r) {
            if (!act[r]) continue;
            float v = x[(size_t)(row0 + r) * vocab + i];
            if (v > best[r]) { best[r] = v; bidx[r] = i; }
        }
    }

    // Wave butterfly reduce; larger value wins, tie -> lower index.
#pragma unroll
    for (int off = 32; off >= 1; off >>= 1) {
#pragma unroll
        for (int r = 0; r < R; ++r) {
            float ov = __shfl_down(best[r], off, 64);
            int oi = __shfl_down(bidx[r], off, 64);
            if (ov > best[r] || (ov == best[r] && oi < bidx[r])) {
                best[r] = ov; bidx[r] = oi;
            }
        }
    }

    if (lane == 0) {
#pragma unroll
        for (int r = 0; r < R; ++r) {
            if (act[r]) {
                int* p = ml + (size_t)bb[r] * seq_len + tt[r];
                if (ATOMIC_ML) {
                    __hip_atomic_store(p, bidx[r], __ATOMIC_RELAXED, SCOPE_AGENT);
                } else {
                    *p = bidx[r];
                }
            }
        }
    }
}

// ---------------- compact helper ----------------
// Compact one batch row with 256 threads. Fills its own tokens row with -1
// first (block-local ordering via __syncthreads). ml entries at t >= len are
// never loaded (they may be unwritten garbage).
template <bool ATOMIC_ML>
__device__ __forceinline__ void compact_batch(const int* __restrict__ ml,
                                              const int* __restrict__ lengths,
                                              int blank,
                                              int* __restrict__ tokens,
                                              int* __restrict__ out_lengths,
                                              int b, int seq_len,
                                              int* warp_sums) {
    constexpr int MAXPER = 16;
    const int len = lengths[b];
    const int* row = ml + (size_t)b * seq_len;
    int* out = tokens + (size_t)b * seq_len;

    const int tid = threadIdx.x;
    const int nthr = blockDim.x;

    // -1 fill of this row, vectorized.
    const int nv4 = seq_len >> 2;
    i32x4* out4 = reinterpret_cast<i32x4*>(out);
    for (int i = tid; i < nv4; i += nthr) out4[i] = i32x4{-1, -1, -1, -1};
    for (int i = (nv4 << 2) + tid; i < seq_len; i += nthr) out[i] = -1;
    __syncthreads();

    const int per = (seq_len + nthr - 1) / nthr;  // 8 for 2048/256

    const int t0 = tid * per;
    int vals[MAXPER];
    unsigned keep_mask = 0;
    int cnt = 0;
    int prev = -1;
    if (t0 > 0 && t0 - 1 < len) {
        prev = ATOMIC_ML
                   ? __hip_atomic_load(row + t0 - 1, __ATOMIC_RELAXED, SCOPE_AGENT)
                   : row[t0 - 1];
    }
    for (int j = 0; j < per; ++j) {
        const int t = t0 + j;
        if (t >= seq_len) break;
        int v = -2;
        if (t < len) {
            v = ATOMIC_ML
                    ? __hip_atomic_load(row + t, __ATOMIC_RELAXED, SCOPE_AGENT)
                    : row[t];
        }
        const bool k = (t < len) && (v != blank) && (prev == blank || v != prev);
        vals[j] = v;
        if (k) { keep_mask |= (1u << j); ++cnt; }
        prev = v;
    }

    // Block-wide exclusive prefix sum of cnt (thread order).
    const int lane = tid & 63;
    const int wid = tid >> 6;
    int incl = cnt;
#pragma unroll
    for (int off = 1; off < 64; off <<= 1) {
        int n = __shfl_up(incl, off, 64);
        if (lane >= off) incl += n;
    }
    if (lane == 63) warp_sums[wid] = incl;
    __syncthreads();

    int wbase = 0;
    for (int w = 0; w < wid; ++w) wbase += warp_sums[w];
    int pos = wbase + incl - cnt;

    for (int j = 0; j < per; ++j) {
        if (keep_mask & (1u << j)) out[pos++] = vals[j];
    }

    if (tid == 0) {
        int total = 0;
        const int nwaves = nthr >> 6;
        for (int w = 0; w < nwaves; ++w) total += warp_sums[w];
        out_lengths[b] = total;
    }
}

// ---------------- fused single kernel (atomic-flag sync) ----------------
template <int R>
__global__ __launch_bounds__(256) void ctc_fused_kernel(
    const float* __restrict__ x,
    int* __restrict__ ml,
    unsigned* __restrict__ ctr,     // memset to 0 before launch
    const int* __restrict__ lengths,
    const int* __restrict__ blank_ptr,
    int* __restrict__ tokens,
    int* __restrict__ out_lengths,
    int seq_len, int batch, int vocab) {
    __shared__ int warp_sums[8];

    const int nrows = seq_len * batch;
    const int lane = threadIdx.x & 63;
    const int wave = blockIdx.x * (blockDim.x >> 6) + (threadIdx.x >> 6);
    const int row0 = wave * R;

    if (row0 < nrows) {
        argmax_tasks<R, true>(x, ml, lengths, row0, nrows, seq_len, batch,
                              vocab, lane);
    }

    // Drain this block's ml stores (syncthreads waits vmcnt(0)), then signal.
    __syncthreads();
    if (threadIdx.x == 0) {
        __hip_atomic_fetch_add(ctr, 1u, __ATOMIC_RELEASE, SCOPE_AGENT);
    }

    // Consumer blocks: wait for all blocks, then compact one batch row.
    const int b = blockIdx.x;
    if (b < batch) {
        if (threadIdx.x == 0) {
            while (__hip_atomic_load(ctr, __ATOMIC_ACQUIRE, SCOPE_AGENT) <
                   (unsigned)gridDim.x) {
                __builtin_amdgcn_s_sleep(2);
            }
        }
        __syncthreads();
        compact_batch<true>(ml, lengths, *blank_ptr, tokens, out_lengths, b,
                            seq_len, warp_sums);
    }
}

// ---------------- fallback two-kernel path ----------------
template <int R>
__global__ __launch_bounds__(256) void ctc_argmax_kernel(
    const float* __restrict__ x, int* __restrict__ ml,
    const int* __restrict__ lengths,
    int seq_len, int batch, int vocab) {
    const int nrows = seq_len * batch;
    const int lane = threadIdx.x & 63;
    const int wave = blockIdx.x * (blockDim.x >> 6) + (threadIdx.x >> 6);
    const int row0 = wave * R;
    if (row0 >= nrows) return;
    argmax_tasks<R, false>(x, ml, lengths, row0, nrows, seq_len, batch, vocab,
                           lane);
}

__global__ __launch_bounds__(256) void ctc_compact_kernel(
    const int* __restrict__ ml, const int* __restrict__ lengths,
    const int* __restrict__ blank_ptr, int* __restrict__ tokens,
    int* __restrict__ out_lengths, int seq_len, int batch) {
    __shared__ int warp_sums[8];
    const int b = blockIdx.x;
    if (b >= batch) return;
    compact_batch<false>(ml, lengths, *blank_ptr, tokens, out_lengths, b,
                         seq_len, warp_sums);
}

// ---------------- host ----------------
extern "C" void kernel_launch(void* const* d_in, const int* in_sizes, int n_in,
                              void* d_out, int out_size, void* d_ws, size_t ws_size,
                              hipStream_t stream) {
    const float* x = (const float*)d_in[0];
    const int* lengths = (const int*)d_in[1];
    const int* blank_ptr = (const int*)d_in[2];

    const int batch = in_sizes[1];
    const int seq_len = (out_size - batch) / batch;  // tokens is (batch, seq_len)
    const int vocab = in_sizes[0] / (seq_len * batch);

    int* tokens = (int*)d_out;                                 // (batch, seq_len)
    int* out_lengths = (int*)d_out + (size_t)batch * seq_len;  // (batch,)

    int* ml = (int*)d_ws;                                      // (batch, seq_len)
    const size_t ml_bytes = (size_t)batch * seq_len * sizeof(int);
    unsigned* ctr = (unsigned*)((char*)d_ws + ((ml_bytes + 255) & ~(size_t)255));

    constexpr int R = 4;
    const int nrows = seq_len * batch;
    const int ntasks = (nrows + R - 1) / R;
    const int waves_per_block = 4;
    const int blocks = (ntasks + waves_per_block - 1) / waves_per_block;

    const bool fused_ok =
        (batch <= blocks) && (batch <= 1024) &&
        (ml_bytes + 256 + sizeof(unsigned) <= ws_size);

    if (fused_ok) {
        hipMemsetAsync(ctr, 0, sizeof(unsigned), stream);
        ctc_fused_kernel<R><<<blocks, waves_per_block * 64, 0, stream>>>(
            x, ml, ctr, lengths, blank_ptr, tokens, out_lengths,
            seq_len, batch, vocab);
    } else {
        ctc_argmax_kernel<R><<<blocks, waves_per_block * 64, 0, stream>>>(
            x, ml, lengths, seq_len, batch, vocab);
        ctc_compact_kernel<<<batch, 256, 0, stream>>>(
            ml, lengths, blank_ptr, tokens, out_lengths, seq_len, batch);
    }
}

// Round 7
// 23.874 us; speedup vs baseline: 4.6629x; 4.6629x over previous
//
#include <hip/hip_runtime.h>
#include <hip/hip_bf16.h>
#include <float.h>

typedef float f32x4 __attribute__((ext_vector_type(4)));

// Kernel 1: argmax over vocab for each (t, b) row.
// x layout: (seq_len, batch, vocab) row-major; row = t*batch + b.
// Intra-wave layout: 4 rows per wave, 16 lanes per row (lane>>4 = row group,
// lane&15 = sub-lane). Each lane scans vocab/16 elements of its row; the
// argmax reduce is 4 __shfl_xor steps for all 4 rows in parallel.
// Rows with t >= lengths[b] are skipped (never consumed downstream).
// Output ml stored TRANSPOSED: ml[b*seq_len + t]. Also fills tokens with -1.
__global__ __launch_bounds__(256) void ctc_argmax_kernel(
    const float* __restrict__ x,
    int* __restrict__ ml,
    const int* __restrict__ lengths,
    int* __restrict__ tokens,
    int seq_len, int batch, int vocab) {
    const int nrows = seq_len * batch;

    // -1 fill of tokens (batch*seq_len ints), grid-strided.
    const int gtid = blockIdx.x * blockDim.x + threadIdx.x;
    const int gstride = gridDim.x * blockDim.x;
    for (int i = gtid; i < nrows; i += gstride) tokens[i] = -1;

    const int lane = threadIdx.x & 63;
    const int wave = blockIdx.x * (blockDim.x >> 6) + (threadIdx.x >> 6);
    const int row0 = wave * 4;
    if (row0 >= nrows) return;

    const int g = lane >> 4;    // row group 0..3
    const int sl = lane & 15;   // sub-lane within group
    const int row = row0 + g;

    bool act = false;
    int t = 0, b = 0;
    if (row < nrows) {
        t = row / batch;
        b = row - t * batch;
        act = (t < lengths[b]);   // uniform within the 16-lane group
    }
    if (!__any(act)) return;

    float best = -FLT_MAX;
    int bidx = vocab;

    if (act) {
        const int vmain = vocab & ~63;   // multiple of 64 floats (16 lanes x 4)
        const float* p = x + (size_t)row * vocab + sl * 4;
        for (int base = 0; base < vmain; base += 64) {
            f32x4 v = *reinterpret_cast<const f32x4*>(p + base);
            const int i0 = base + sl * 4;
#pragma unroll
            for (int j = 0; j < 4; ++j) {
                if (v[j] > best) { best = v[j]; bidx = i0 + j; }
            }
        }
        // Scalar tail (vocab % 64 != 0); tail indices exceed main indices,
        // strict '>' keeps the earlier occurrence; ties resolved in reduce.
        for (int i = vmain + sl; i < vocab; i += 16) {
            float v = x[(size_t)row * vocab + i];
            if (v > best) { best = v; bidx = i; }
        }
    }

    // 4-step xor reduce within each 16-lane group (all 4 rows in parallel).
    // Larger value wins; on tie, lower index wins (first occurrence).
#pragma unroll
    for (int m = 1; m <= 8; m <<= 1) {
        float ov = __shfl_xor(best, m, 64);
        int oi = __shfl_xor(bidx, m, 64);
        if (ov > best || (ov == best && oi < bidx)) { best = ov; bidx = oi; }
    }

    if (act && sl == 0) {
        ml[(size_t)b * seq_len + t] = bidx;
    }
}

// Kernel 2: per-batch removal of blanks and consecutive duplicates + left-pack.
// One block (256 threads) per batch element. tokens[] pre-filled with -1.
// ml entries at t >= lengths[b] may be garbage; keep=false there, and prev at
// any kept t reads t-1 < len, so garbage never influences the output.
__global__ __launch_bounds__(256) void ctc_compact_kernel(
    const int* __restrict__ ml,
    const int* __restrict__ lengths,
    const int* __restrict__ blank_ptr,
    int* __restrict__ tokens,
    int* __restrict__ out_lengths,
    int seq_len, int batch) {
    constexpr int MAXPER = 16;
    const int b = blockIdx.x;
    if (b >= batch) return;
    const int blank = *blank_ptr;
    const int len = lengths[b];
    const int* row = ml + (size_t)b * seq_len;
    int* out = tokens + (size_t)b * seq_len;

    const int tid = threadIdx.x;
    const int nthr = blockDim.x;
    const int per = (seq_len + nthr - 1) / nthr;  // 8 for 2048/256

    const int t0 = tid * per;
    int vals[MAXPER];
    unsigned keep_mask = 0;
    int cnt = 0;
    int prev = (t0 == 0) ? -1 : ((t0 - 1 < seq_len) ? row[t0 - 1] : -1);
    for (int j = 0; j < per; ++j) {
        const int t = t0 + j;
        if (t >= seq_len) break;
        const int v = row[t];
        const bool valid = t < len;
        const bool k = valid && (v != blank) && (prev == blank || v != prev);
        vals[j] = v;
        if (k) { keep_mask |= (1u << j); ++cnt; }
        prev = v;
    }

    // Block-wide exclusive prefix sum of cnt (thread order).
    __shared__ int warp_sums[8];
    const int lane = tid & 63;
    const int wid = tid >> 6;
    int incl = cnt;
#pragma unroll
    for (int off = 1; off < 64; off <<= 1) {
        int n = __shfl_up(incl, off, 64);
        if (lane >= off) incl += n;
    }
    if (lane == 63) warp_sums[wid] = incl;
    __syncthreads();

    int wbase = 0;
    for (int w = 0; w < wid; ++w) wbase += warp_sums[w];
    int pos = wbase + incl - cnt;  // exclusive prefix for this thread

    for (int j = 0; j < per; ++j) {
        if (keep_mask & (1u << j)) out[pos++] = vals[j];
    }

    if (tid == 0) {
        int total = 0;
        const int nwaves = nthr >> 6;
        for (int w = 0; w < nwaves; ++w) total += warp_sums[w];
        out_lengths[b] = total;
    }
}

extern "C" void kernel_launch(void* const* d_in, const int* in_sizes, int n_in,
                              void* d_out, int out_size, void* d_ws, size_t ws_size,
                              hipStream_t stream) {
    const float* x = (const float*)d_in[0];
    const int* lengths = (const int*)d_in[1];
    const int* blank_ptr = (const int*)d_in[2];

    const int batch = in_sizes[1];
    const int seq_len = (out_size - batch) / batch;      // tokens is (batch, seq_len)
    const int vocab = in_sizes[0] / (seq_len * batch);

    int* tokens = (int*)d_out;                                  // (batch, seq_len)
    int* out_lengths = (int*)d_out + (size_t)batch * seq_len;   // (batch,)
    int* ml = (int*)d_ws;                                       // (batch, seq_len)

    // Kernel 1: 4 rows per wave (16 lanes each), 4 waves per 256-thread block.
    const int nrows = seq_len * batch;
    const int ntasks = (nrows + 3) / 4;
    const int waves_per_block = 4;
    const int blocks1 = (ntasks + waves_per_block - 1) / waves_per_block;
    ctc_argmax_kernel<<<blocks1, waves_per_block * 64, 0, stream>>>(
        x, ml, lengths, tokens, seq_len, batch, vocab);

    // Kernel 2: one block per batch element.
    ctc_compact_kernel<<<batch, 256, 0, stream>>>(
        ml, lengths, blank_ptr, tokens, out_lengths, seq_len, batch);
}

// Round 8
// 20.914 us; speedup vs baseline: 5.3229x; 1.1415x over previous
//
#include <hip/hip_runtime.h>
#include <hip/hip_bf16.h>
#include <float.h>

typedef float f32x4 __attribute__((ext_vector_type(4)));
typedef int i32x4 __attribute__((ext_vector_type(4)));

// Kernel 1: argmax over vocab for each (t, b) row.
// x layout: (seq_len, batch, vocab) row-major; row = t*batch + b.
// Intra-wave layout: 8 rows per wave, 8 lanes per row (lane>>3 = row group,
// lane&7 = sub-lane). Each lane scans vocab/8 elements of its row; the
// argmax reduce is 3 __shfl_xor steps for all 8 rows in parallel.
// Rows with t >= lengths[b] are skipped (never consumed downstream).
// Output ml stored TRANSPOSED: ml[b*seq_len + t]. Also fills tokens with -1.
__global__ __launch_bounds__(256) void ctc_argmax_kernel(
    const float* __restrict__ x,
    int* __restrict__ ml,
    const int* __restrict__ lengths,
    int* __restrict__ tokens,
    int seq_len, int batch, int vocab) {
    const int nrows = seq_len * batch;

    // -1 fill of tokens (batch*seq_len ints), grid-strided.
    const int gtid = blockIdx.x * blockDim.x + threadIdx.x;
    const int gstride = gridDim.x * blockDim.x;
    for (int i = gtid; i < nrows; i += gstride) tokens[i] = -1;

    const int lane = threadIdx.x & 63;
    const int wave = blockIdx.x * (blockDim.x >> 6) + (threadIdx.x >> 6);
    const int row0 = wave * 8;
    if (row0 >= nrows) return;

    const int g = lane >> 3;    // row group 0..7
    const int sl = lane & 7;    // sub-lane within group
    const int row = row0 + g;

    bool act = false;
    int t = 0, b = 0;
    if (row < nrows) {
        t = row / batch;
        b = row - t * batch;
        act = (t < lengths[b]);   // uniform within the 8-lane group
    }
    if (!__any(act)) return;

    float best = -FLT_MAX;
    int bidx = vocab;

    if (act) {
        const int vmain = vocab & ~31;   // multiple of 32 floats (8 lanes x 4)
        const float* p = x + (size_t)row * vocab + sl * 4;
        for (int base = 0; base < vmain; base += 32) {
            f32x4 v = *reinterpret_cast<const f32x4*>(p + base);
            const int i0 = base + sl * 4;
#pragma unroll
            for (int j = 0; j < 4; ++j) {
                if (v[j] > best) { best = v[j]; bidx = i0 + j; }
            }
        }
        // Scalar tail (vocab % 32 != 0); tail indices exceed main indices,
        // strict '>' keeps the earlier occurrence; ties resolved in reduce.
        for (int i = vmain + sl; i < vocab; i += 8) {
            float v = x[(size_t)row * vocab + i];
            if (v > best) { best = v; bidx = i; }
        }
    }

    // 3-step xor reduce within each 8-lane group (all 8 rows in parallel).
    // Larger value wins; on tie, lower index wins (first occurrence).
#pragma unroll
    for (int m = 1; m <= 4; m <<= 1) {
        float ov = __shfl_xor(best, m, 64);
        int oi = __shfl_xor(bidx, m, 64);
        if (ov > best || (ov == best && oi < bidx)) { best = ov; bidx = oi; }
    }

    if (act && sl == 0) {
        ml[(size_t)b * seq_len + t] = bidx;
    }
}

// Kernel 2: per-batch removal of blanks and consecutive duplicates + left-pack.
// One block (512 threads) per batch element. tokens[] pre-filled with -1.
// ml entries at t >= lengths[b] may be garbage; keep=false there, and prev at
// any kept t reads t-1 < len, so garbage never influences the output.
__global__ __launch_bounds__(512) void ctc_compact_kernel(
    const int* __restrict__ ml,
    const int* __restrict__ lengths,
    const int* __restrict__ blank_ptr,
    int* __restrict__ tokens,
    int* __restrict__ out_lengths,
    int seq_len, int batch) {
    constexpr int MAXPER = 16;
    const int b = blockIdx.x;
    if (b >= batch) return;
    const int blank = *blank_ptr;
    const int len = lengths[b];
    const int* row = ml + (size_t)b * seq_len;
    int* out = tokens + (size_t)b * seq_len;

    const int tid = threadIdx.x;
    const int nthr = blockDim.x;
    const int per = (seq_len + nthr - 1) / nthr;  // 4 for 2048/512

    const int t0 = tid * per;
    int vals[MAXPER];
    unsigned keep_mask = 0;
    int cnt = 0;

    if (per == 4 && t0 + 4 <= seq_len && (seq_len & 3) == 0) {
        // Fast path: one aligned int4 load for this thread's 4 timesteps.
        i32x4 v4 = *reinterpret_cast<const i32x4*>(row + t0);
        int prev = (t0 == 0) ? -1 : row[t0 - 1];
#pragma unroll
        for (int j = 0; j < 4; ++j) {
            const int t = t0 + j;
            const int v = v4[j];
            const bool k = (t < len) && (v != blank) &&
                           (prev == blank || v != prev);
            vals[j] = v;
            if (k) { keep_mask |= (1u << j); ++cnt; }
            prev = v;
        }
    } else {
        int prev = (t0 == 0) ? -1 : ((t0 - 1 < seq_len) ? row[t0 - 1] : -1);
        for (int j = 0; j < per && j < MAXPER; ++j) {
            const int t = t0 + j;
            if (t >= seq_len) break;
            const int v = row[t];
            const bool k = (t < len) && (v != blank) &&
                           (prev == blank || v != prev);
            vals[j] = v;
            if (k) { keep_mask |= (1u << j); ++cnt; }
            prev = v;
        }
    }

    // Block-wide exclusive prefix sum of cnt (thread order).
    __shared__ int warp_sums[8];
    const int lane = tid & 63;
    const int wid = tid >> 6;
    int incl = cnt;
#pragma unroll
    for (int off = 1; off < 64; off <<= 1) {
        int n = __shfl_up(incl, off, 64);
        if (lane >= off) incl += n;
    }
    if (lane == 63) warp_sums[wid] = incl;
    __syncthreads();

    int wbase = 0;
    for (int w = 0; w < wid; ++w) wbase += warp_sums[w];
    int pos = wbase + incl - cnt;  // exclusive prefix for this thread

    for (int j = 0; j < per && j < MAXPER; ++j) {
        if (keep_mask & (1u << j)) out[pos++] = vals[j];
    }

    if (tid == 0) {
        int total = 0;
        const int nwaves = nthr >> 6;
        for (int w = 0; w < nwaves; ++w) total += warp_sums[w];
        out_lengths[b] = total;
    }
}

extern "C" void kernel_launch(void* const* d_in, const int* in_sizes, int n_in,
                              void* d_out, int out_size, void* d_ws, size_t ws_size,
                              hipStream_t stream) {
    const float* x = (const float*)d_in[0];
    const int* lengths = (const int*)d_in[1];
    const int* blank_ptr = (const int*)d_in[2];

    const int batch = in_sizes[1];
    const int seq_len = (out_size - batch) / batch;      // tokens is (batch, seq_len)
    const int vocab = in_sizes[0] / (seq_len * batch);

    int* tokens = (int*)d_out;                                  // (batch, seq_len)
    int* out_lengths = (int*)d_out + (size_t)batch * seq_len;   // (batch,)
    int* ml = (int*)d_ws;                                       // (batch, seq_len)

    // Kernel 1: 8 rows per wave (8 lanes each), 4 waves per 256-thread block.
    const int nrows = seq_len * batch;
    const int ntasks = (nrows + 7) / 8;
    const int waves_per_block = 4;
    const int blocks1 = (ntasks + waves_per_block - 1) / waves_per_block;
    ctc_argmax_kernel<<<blocks1, waves_per_block * 64, 0, stream>>>(
        x, ml, lengths, tokens, seq_len, batch, vocab);

    // Kernel 2: one block per batch element, 512 threads.
    ctc_compact_kernel<<<batch, 512, 0, stream>>>(
        ml, lengths, blank_ptr, tokens, out_lengths, seq_len, batch);
}